// Round 12
// baseline (56.071 us; speedup 1.0000x reference)
//
#include <hip/hip_runtime.h>
#include <cstdint>

#define NB 32
#define NROIS 8192
#define NGT 128
#define NALL (NROIS + NGT)   // 8320
#define NSAMP 512
#define KPOS 128
#define KNEG 384
#define BCAP 1024
#define TS 1024              // k_select threads (16 waves)
#define CH 9                 // ceil(NALL/TS)

// ---------------- Kernel 0: per-batch cell->gt overlap masks -----------------
// 16x16 grid of 64px cells; cell t holds a 128-bit mask of gts whose box
// overlaps the cell (inclusive tests; edge cells extended to +-inf so the
// mask is a SUPERSET of true box-overlap for ANY input coordinates).
__global__ __launch_bounds__(256) void k_cells(
    const float* __restrict__ gt,          // B,NGT,4
    uint4* __restrict__ cmask)             // B*256 cells
{
  __shared__ float4 sg[NGT];
  const int b = blockIdx.x;
  const int t = threadIdx.x;
  if (t < NGT) sg[t] = reinterpret_cast<const float4*>(gt)[b * NGT + t];
  __syncthreads();

  const int cy = t >> 4, cx = t & 15;
  const float y0 = (cy == 0)  ? -3.0e38f : cy * 64.0f;
  const float y1 = (cy == 15) ?  3.0e38f : (cy + 1) * 64.0f;
  const float x0 = (cx == 0)  ? -3.0e38f : cx * 64.0f;
  const float x1 = (cx == 15) ?  3.0e38f : (cx + 1) * 64.0f;

  unsigned mm[4] = {0u, 0u, 0u, 0u};
  #pragma unroll
  for (int j = 0; j < NGT; ++j) {
    const float4 g = sg[j];
    const bool ov = (g.x <= y1) && (g.z >= y0) && (g.y <= x1) && (g.w >= x0);
    mm[j >> 5] |= ((unsigned)ov) << (j & 31);
  }
  uint4 o; o.x = mm[0]; o.y = mm[1]; o.z = mm[2]; o.w = mm[3];
  cmask[(size_t)b * 256 + t] = o;
}

// ---------------- Kernel 1: IoU matching (cell-pruned cross-mul argmax) ------
// 256 thr/block, 1 roi/thread, grid (33,32). Each roi ORs the cell masks its
// box covers (superset of overlapping gts) and evaluates ONLY set bits,
// ascending -> identical first-max/tie semantics as the full scan (validated
// R9/R11): zero-inter candidates never beat (bi=0,bc=0), all-pruned rois keep
// cc=0 = reference argmax of an all-zero row. Cross-mul ordering (no div);
// ONE contract-off IEEE div on the winner gives bit-exact >=0.5/>=0.0 codes.
// Any masked [-1,-1,-1,-1] box in batch/block -> full-scan slow path.
__global__ __launch_bounds__(256) void k_match(
    const float* __restrict__ rois,   // B,NROIS,4
    const float* __restrict__ gt,     // B,NGT,4
    const float* __restrict__ noise,  // B,NALL,2
    const uint4* __restrict__ cmask,  // B*256
    int* __restrict__ mword)          // B*NALL : col | code<<7 | bin<<9
{
  __shared__ float4 sg[NGT];
  __shared__ float sab[NGT];           // areas (slow path only)
  __shared__ uint4 scm[256];
  __shared__ int s_any;

  const int b = blockIdx.y;
  const int tid = threadIdx.x;
  const float4* gt4 = reinterpret_cast<const float4*>(gt) + (size_t)b * NGT;
  const float4* rois4 = reinterpret_cast<const float4*>(rois) + (size_t)b * NROIS;

  if (tid == 0) s_any = 0;
  bool mflag = false;
  if (tid < NGT) {
    float4 g0 = gt4[tid];
    sg[tid] = g0;
    sab[tid] = (g0.z - g0.x) * (g0.w - g0.y);
    mflag = (g0.x == -1.0f) && (g0.y == -1.0f) && (g0.z == -1.0f) && (g0.w == -1.0f);
  }
  scm[tid] = cmask[(size_t)b * 256 + tid];

  const int i = blockIdx.x * 256 + tid;   // 33*256 = 8448 >= 8320
  const bool act = (i < NALL);
  float4 A = act ? ((i < NROIS) ? rois4[i] : gt4[i - NROIS]) : rois4[0];
  const float aar = (A.z - A.x) * (A.w - A.y);
  const bool ma = act && (A.x == -1.0f) && (A.y == -1.0f) && (A.z == -1.0f) && (A.w == -1.0f);

  __syncthreads();                       // s_any init + sg/scm staged
  if (mflag || ma) atomicOr(&s_any, 1);
  __syncthreads();                       // s_any final (block-uniform)

  if (!act) return;

  int cc;      // argmax col
  int code;    // 3=pos, 1=neg, 0=ignore

  if (s_any == 0) {
    // ---- cell range covered by this roi (clamped; edge cells are +-inf) ----
    const float inv = 1.0f / 64.0f;
    int cy0 = (int)(A.x * inv), cy1 = (int)(A.z * inv);
    int cx0 = (int)(A.y * inv), cx1 = (int)(A.w * inv);
    cy0 = cy0 < 0 ? 0 : (cy0 > 15 ? 15 : cy0);
    cy1 = cy1 < 0 ? 0 : (cy1 > 15 ? 15 : cy1);
    cx0 = cx0 < 0 ? 0 : (cx0 > 15 ? 15 : cx0);
    cx1 = cx1 < 0 ? 0 : (cx1 > 15 ? 15 : cx1);

    unsigned mm0 = 0u, mm1 = 0u, mm2 = 0u, mm3 = 0u;
    for (int cy = cy0; cy <= cy1; ++cy) {
      for (int cx = cx0; cx <= cx1; ++cx) {
        const uint4 cm = scm[(cy << 4) + cx];
        mm0 |= cm.x; mm1 |= cm.y; mm2 |= cm.z; mm3 |= cm.w;
      }
    }

    float bi = 0.0f, bu = 1.0f;
    int bc = 0;
    auto eval = [&](int j) {
      const float4 g = sg[j];
      const float ab = (g.z - g.x) * (g.w - g.y);
      float iy = fmaxf(fminf(A.z, g.z) - fmaxf(A.x, g.x), 0.0f);
      float ix = fmaxf(fminf(A.w, g.w) - fmaxf(A.y, g.y), 0.0f);
      float inter = iy * ix;
      float uc = fmaxf((aar + ab) - inter, 1e-8f);
      const bool win = (inter * bu) > (bi * uc);   // iou_j > iou_best
      bi = win ? inter : bi;
      bu = win ? uc : bu;
      bc = win ? j : bc;
    };
    // evaluate candidates in ASCENDING j (first-max semantics preserved)
    { unsigned m = mm0; while (m) { const int j =      __builtin_ctz(m); m &= m - 1; eval(j); } }
    { unsigned m = mm1; while (m) { const int j = 32 + __builtin_ctz(m); m &= m - 1; eval(j); } }
    { unsigned m = mm2; while (m) { const int j = 64 + __builtin_ctz(m); m &= m - 1; eval(j); } }
    { unsigned m = mm3; while (m) { const int j = 96 + __builtin_ctz(m); m &= m - 1; eval(j); } }
    cc = bc;

    // exact threshold: one contract-off IEEE div on the winner
    {
      #pragma clang fp contract(off)
      const float4 g = sg[cc];
      float iy = fmaxf(fminf(A.z, g.z) - fmaxf(A.x, g.x), 0.0f);
      float ix = fmaxf(fminf(A.w, g.w) - fmaxf(A.y, g.y), 0.0f);
      float inter = iy * ix;
      float ab = (g.z - g.x) * (g.w - g.y);
      float uni = (aar + ab) - inter;
      float bb = inter / fmaxf(uni, 1e-8f);   // IEEE-exact, matches reference max
      code = (bb >= 0.5f) ? 3 : ((bb >= 0.0f) ? 1 : 0);
    }
  } else {
    // ---- slow path (masked boxes; never taken for this data) ----
    #pragma clang fp contract(off)
    float bb = -3.0e38f;
    cc = 0;
    for (int j = 0; j < NGT; ++j) {
      float4 gg = sg[j];
      const bool mj = (gg.x == -1.0f) && (gg.y == -1.0f) && (gg.z == -1.0f) && (gg.w == -1.0f);
      float iy = fmaxf(fminf(A.z, gg.z) - fmaxf(A.x, gg.x), 0.0f);
      float ix = fmaxf(fminf(A.w, gg.w) - fmaxf(A.y, gg.y), 0.0f);
      float inter = iy * ix;
      float uni = (aar + sab[j]) - inter;
      float iou = inter / fmaxf(uni, 1e-8f);
      if (ma || mj) iou = -1.0f;
      if (iou > bb) { bb = iou; cc = j; }   // ascending strict > = first-max
    }
    code = (bb >= 0.5f) ? 3 : ((bb >= 0.0f) ? 1 : 0);
  }

  float2 nz = reinterpret_cast<const float2*>(noise)[(size_t)b * NALL + i];
  float v = (code == 3) ? nz.x : nz.y;
  int bin = (int)(v * 1024.0f);
  bin = bin < 0 ? 0 : (bin > 1023 ? 1023 : bin);
  mword[(size_t)b * NALL + i] = cc | (code << 7) | (bin << 9);
}

// ---------------- shfl-based block inclusive scan (TS=1024, 16 waves) -------
__device__ __forceinline__ int block_incl_scan(int v, int tid, int* wsum) {
  __syncthreads();  // protect wsum reuse across consecutive calls
  int s = v;
  #pragma unroll
  for (int off = 1; off < 64; off <<= 1) {
    int u = __shfl_up(s, off);
    if ((tid & 63) >= off) s += u;
  }
  const int wid = tid >> 6;
  if ((tid & 63) == 63) wsum[wid] = s;
  __syncthreads();
  if (wid == 0) {
    const int lane = tid & 63;
    int w = (lane < (TS >> 6)) ? wsum[lane] : 0;
    #pragma unroll
    for (int off = 1; off < (TS >> 6); off <<= 1) {
      int u = __shfl_up(w, off);
      if (lane >= off) w += u;
    }
    if (lane < (TS >> 6)) wsum[lane] = w;
  }
  __syncthreads();
  return s + (wid ? wsum[wid - 1] : 0);
}

// ---------------- Kernel 2: balanced sampling + ordering + gather ------------
__global__ __launch_bounds__(TS) void k_select(
    const int* __restrict__ mword,
    const float* __restrict__ noise,  // B,NALL,2
    const float* __restrict__ rois,
    const float* __restrict__ gt,
    const float* __restrict__ gtcls,  // B,NGT,1
    float* __restrict__ out)
{
  #pragma clang fp contract(off)
  const int b = blockIdx.x;
  const int tid = threadIdx.x;

  __shared__ int hist[1024];            // packed pos|neg<<16
  __shared__ int wsum[TS >> 6];
  __shared__ int s_total;               // packed totals
  __shared__ float bval[2][BCAP];
  __shared__ int bidx_[2][BCAP];
  __shared__ int bcnt[2];
  __shared__ int s_bstar[2], s_need[2];
  __shared__ unsigned char ind[NALL];
  __shared__ unsigned short sorder[NSAMP];

  int ew[CH];     // packed word; bit7 set => candidate

  hist[tid] = 0;
  if (tid < 2) bcnt[tid] = 0;

  // ---- pass 1: one int load per element; histogram + ind init ----
  #pragma unroll
  for (int k = 0; k < CH; ++k) {
    const int i = tid + k * TS;
    int w = 0;
    if (i < NALL) {
      ind[i] = 0;
      w = mword[(size_t)b * NALL + i];
    }
    ew[k] = w;
  }
  __syncthreads();
  #pragma unroll
  for (int k = 0; k < CH; ++k) {
    const int w = ew[k];
    if (w & 0x80) atomicAdd(&hist[w >> 9], (w & 0x100) ? 1 : (1 << 16));
  }
  __syncthreads();

  // ---- packed suffix scan, one bin per thread ----
  const int c = hist[tid];
  const int incl = block_incl_scan(c, tid, wsum);
  if (tid == TS - 1) s_total = incl;
  __syncthreads();
  const int total = s_total;

  #pragma unroll
  for (int p = 0; p < 2; ++p) {
    const int want = p ? KNEG : KPOS;
    const int sh = p ? 16 : 0;
    const int tot = (total >> sh) & 0xFFFF;
    if (tot >= want) {                              // !selall
      const int inc = (incl >> sh) & 0xFFFF;
      const int cp = (c >> sh) & 0xFFFF;
      const int above = tot - inc;                  // sum of bins > tid
      if (above < want && above + cp >= want) {     // unique boundary thread
        s_bstar[p] = tid; s_need[p] = want - above;
      }
    }
  }
  __syncthreads();

  const bool selall0 = ((total & 0xFFFF) < KPOS);
  const bool selall1 = (((total >> 16) & 0xFFFF) < KNEG);

  // ---- mark: bins above boundary selected; boundary bins collected ----
  #pragma unroll
  for (int k = 0; k < CH; ++k) {
    const int w = ew[k];
    if (w & 0x80) {
      const int i = tid + k * TS;
      const int p = (w & 0x100) ? 0 : 1;
      const bool selall = p ? selall1 : selall0;
      const int bin = w >> 9;
      if (selall || bin > s_bstar[p]) {
        ind[i] = 1;
      } else if (bin == s_bstar[p]) {
        int pos = atomicAdd(&bcnt[p], 1);
        if (pos < BCAP) {
          bval[p][pos] = noise[((size_t)b * NALL + i) * 2 + p];  // rare reload
          bidx_[p][pos] = i;
        }
      }
    }
  }
  __syncthreads();

  // ---- boundary-bin exact top-k via parallel rank (value desc, idx asc) ----
  #pragma unroll
  for (int p = 0; p < 2; ++p) {
    const bool selall = p ? selall1 : selall0;
    if (selall) continue;
    int cnt = bcnt[p]; if (cnt > BCAP) cnt = BCAP;
    const int need = s_need[p];
    for (int x = tid; x < cnt; x += TS) {
      const float v = bval[p][x];
      const int id = bidx_[p][x];
      int rank = 0;
      for (int y = 0; y < cnt; ++y) {
        const float vy = bval[p][y];
        const int iy2 = bidx_[p][y];
        rank += (vy > v) || (vy == v && iy2 < id);
      }
      if (rank < need) ind[id] = 1;
    }
  }
  __syncthreads();

  // ---- ordering: ones ascending then zeros ascending (top_k of 0/1) ----
  const int start = tid * CH;
  const int end = (start + CH < NALL) ? (start + CH) : NALL;
  int cnt1 = 0;
  for (int i = start; i < end; ++i) cnt1 += ind[i];
  const int incl1 = block_incl_scan(cnt1, tid, wsum);
  if (tid == TS - 1) s_total = incl1;
  __syncthreads();
  const int K1 = s_total;
  int ones_before = incl1 - cnt1;
  const int nzero = NSAMP - K1;
  for (int i = start; i < end; ++i) {
    if (ind[i]) {
      sorder[ones_before] = (unsigned short)i;
      ones_before++;
    } else {
      const int zrank = i - ones_before;
      if (zrank < nzero) sorder[K1 + zrank] = (unsigned short)i;
    }
  }
  __syncthreads();

  // ---- fused gather + encode + write (one sample per thread) ----
  if (tid < NSAMP) {
    const int s = tid;
    const int idx = sorder[s];
    const size_t t = (size_t)b * NSAMP + s;

    float4 A = (idx < NROIS)
      ? reinterpret_cast<const float4*>(rois)[(size_t)b * NROIS + idx]
      : reinterpret_cast<const float4*>(gt)[(size_t)b * NGT + (idx - NROIS)];

    const int w = mword[(size_t)b * NALL + idx];
    const int col = w & 0x7F;
    const bool pos = (((w >> 7) & 3) == 3);

    float e0 = 0.f, e1 = 0.f, e2 = 0.f, e3 = 0.f, cls = 0.f;
    if (pos) {
      float4 G = reinterpret_cast<const float4*>(gt)[(size_t)b * NGT + col];
      float ah = A.z - A.x, aw = A.w - A.y;
      float acy = A.x + 0.5f * ah, acx = A.y + 0.5f * aw;
      float bh = G.z - G.x, bw = G.w - G.y;
      float bcy = G.x + 0.5f * bh, bcx = G.y + 0.5f * bw;
      e0 = ((bcy - acy) / ah) / 0.1f;
      e1 = ((bcx - acx) / aw) / 0.1f;
      e2 = logf(bh / ah) / 0.2f;
      e3 = logf(bw / aw) / 0.2f;
      cls = gtcls[(size_t)b * NGT + col];
    }

    float* o_rois = out;                           // NB*NSAMP*4
    float* o_enc  = out + (size_t)NB * NSAMP * 4;  // NB*NSAMP*4
    float* o_bw   = out + (size_t)NB * NSAMP * 8;
    float* o_cls  = o_bw + (size_t)NB * NSAMP;
    float* o_cw   = o_cls + (size_t)NB * NSAMP;

    reinterpret_cast<float4*>(o_rois)[t] = A;
    float4 E; E.x = e0; E.y = e1; E.z = e2; E.w = e3;
    reinterpret_cast<float4*>(o_enc)[t] = E;
    o_bw[t]  = pos ? 1.0f : 0.0f;
    o_cls[t] = cls;
    o_cw[t]  = (s < K1) ? 1.0f : 0.0f;
  }
}

extern "C" void kernel_launch(void* const* d_in, const int* in_sizes, int n_in,
                              void* d_out, int out_size, void* d_ws, size_t ws_size,
                              hipStream_t stream) {
  const float* rois  = (const float*)d_in[0];
  const float* gt    = (const float*)d_in[1];
  const float* gtcls = (const float*)d_in[2];
  const float* noise = (const float*)d_in[3];
  float* out = (float*)d_out;

  uint8_t* ws = (uint8_t*)d_ws;
  int* mword = (int*)ws;                                        // NB*NALL ints
  uint4* cmask = (uint4*)(ws + (size_t)NB * NALL * sizeof(int)); // NB*256 uint4

  k_cells<<<NB, 256, 0, stream>>>(gt, cmask);
  dim3 g1((NALL + 255) / 256, NB);  // (33, 32)
  k_match<<<g1, 256, 0, stream>>>(rois, gt, noise, cmask, mword);
  k_select<<<NB, TS, 0, stream>>>(mword, noise, rois, gt, gtcls, out);
}

// Round 13
// 40.339 us; speedup vs baseline: 1.3900x; 1.3900x over previous
//
#include <hip/hip_runtime.h>
#include <cstdint>

#define NB 32
#define NROIS 8192
#define NGT 128
#define NALL (NROIS + NGT)   // 8320
#define NSAMP 512
#define KPOS 128
#define KNEG 384
#define BCAP 1024
#define TS 1024              // k_select threads (16 waves)
#define CH 9                 // ceil(NALL/TS)

// ---------------- Kernel 1: IoU matching (imm-offset cross-mul argmax) -------
// 128 thr/block, 1 roi/thread, grid (65,32) exact -> no bounds guards.
// gt boxes staged in LDS; the hot loop's 32-pair inner body is FULLY unrolled
// so every ds_read_b128 uses an immediate offset off ONE base VGPR that
// advances once per 32 pairs -> zero per-pair address VALU. gt area is
// recomputed in VALU (3 ops) to keep a single LDS op per pair. Two argmax
// chains (j in [0,64), [64,128)) keep registers low; cross-mul ordering
// (iou_j > iou_b <=> inter_j*uc_b > inter_b*uc_j, uc=max(uni,1e-8)>0) with
// ascending strict > preserves first-max; chain0 wins ties (lower j). ONE
// contract-off IEEE div on the winner gives bit-exact >=0.5/>=0.0 codes
// (validated R8-R12). Masked [-1]*4 boxes -> full reference slow path.
__global__ __launch_bounds__(128) void k_match(
    const float* __restrict__ rois,   // B,NROIS,4
    const float* __restrict__ gt,     // B,NGT,4
    const float* __restrict__ noise,  // B,NALL,2
    int* __restrict__ mword)          // B*NALL : col | code<<7 | bin<<9
{
  __shared__ float4 sg[NGT];
  __shared__ float sab[NGT];           // areas (slow path only)
  __shared__ unsigned long long smask[2];

  const int b = blockIdx.y;
  const int tid = threadIdx.x;
  const float4* gt4 = reinterpret_cast<const float4*>(gt) + (size_t)b * NGT;
  const float4* rois4 = reinterpret_cast<const float4*>(rois) + (size_t)b * NROIS;

  // prologue: stage gt boxes + areas + mask ballot (tid covers all 128 gts)
  float4 g0 = gt4[tid];
  sg[tid] = g0;
  sab[tid] = (g0.z - g0.x) * (g0.w - g0.y);
  const bool mflag = (g0.x == -1.0f) && (g0.y == -1.0f) && (g0.z == -1.0f) && (g0.w == -1.0f);
  const unsigned long long mb = __ballot(mflag);
  if ((tid & 63) == 0) smask[tid >> 6] = mb;
  __syncthreads();
  const bool anymask = (smask[0] | smask[1]) != 0ULL;

  const int i = blockIdx.x * 128 + tid;   // 65*128 == NALL exactly
  float4 A = (blockIdx.x < 64) ? rois4[i] : sg[tid];
  const float aar = (A.z - A.x) * (A.w - A.y);
  const bool ma = (A.x == -1.0f) && (A.y == -1.0f) && (A.z == -1.0f) && (A.w == -1.0f);

  int cc;      // argmax col
  int code;    // 3=pos, 1=neg, 0=ignore

  if (!anymask && __ballot(ma) == 0ULL) {
    // ---- fast path: 2 chains, imm-offset LDS reads, cross-mul ordering ----
    float bi0 = 0.0f, bu0 = 1.0f, bi1 = 0.0f, bu1 = 1.0f;
    int bc0 = 0, bc1 = 64;

    for (int jo = 0; jo < 64; jo += 32) {      // 2 outer iters; base adv once
      const float4* p0 = &sg[jo];              // chain0 base (imm offsets 0..31)
      const float4* p1 = &sg[jo + 64];         // chain1 base
      #pragma unroll
      for (int jj = 0; jj < 32; ++jj) {
        {
          const float4 g = p0[jj];             // ds_read_b128, imm offset
          const float ab = (g.z - g.x) * (g.w - g.y);
          float iy = fmaxf(fminf(A.z, g.z) - fmaxf(A.x, g.x), 0.0f);
          float ix = fmaxf(fminf(A.w, g.w) - fmaxf(A.y, g.y), 0.0f);
          float inter = iy * ix;
          float uc = fmaxf((aar + ab) - inter, 1e-8f);
          const bool win = (inter * bu0) > (bi0 * uc);
          bi0 = win ? inter : bi0;
          bu0 = win ? uc : bu0;
          bc0 = win ? (jo + jj) : bc0;
        }
        {
          const float4 g = p1[jj];             // ds_read_b128, imm offset
          const float ab = (g.z - g.x) * (g.w - g.y);
          float iy = fmaxf(fminf(A.z, g.z) - fmaxf(A.x, g.x), 0.0f);
          float ix = fmaxf(fminf(A.w, g.w) - fmaxf(A.y, g.y), 0.0f);
          float inter = iy * ix;
          float uc = fmaxf((aar + ab) - inter, 1e-8f);
          const bool win = (inter * bu1) > (bi1 * uc);
          bi1 = win ? inter : bi1;
          bu1 = win ? uc : bu1;
          bc1 = win ? (jo + 64 + jj) : bc1;
        }
      }
    }
    // merge: chain0 (lower j) wins ties via strict >
    const bool win = (bi1 * bu0) > (bi0 * bu1);
    cc = win ? bc1 : bc0;

    // exact threshold: one contract-off IEEE div on the winner
    {
      #pragma clang fp contract(off)
      const float4 g = sg[cc];
      float iy = fmaxf(fminf(A.z, g.z) - fmaxf(A.x, g.x), 0.0f);
      float ix = fmaxf(fminf(A.w, g.w) - fmaxf(A.y, g.y), 0.0f);
      float inter = iy * ix;
      float ab = (g.z - g.x) * (g.w - g.y);
      float uni = (aar + ab) - inter;
      float bb = inter / fmaxf(uni, 1e-8f);   // IEEE-exact, matches reference max
      code = (bb >= 0.5f) ? 3 : ((bb >= 0.0f) ? 1 : 0);
    }
  } else {
    // ---- slow path (masked boxes; never taken for this data) ----
    #pragma clang fp contract(off)
    float bb = -3.0e38f;
    cc = 0;
    for (int j = 0; j < NGT; ++j) {
      float4 gg = sg[j];
      const bool mj = (gg.x == -1.0f) && (gg.y == -1.0f) && (gg.z == -1.0f) && (gg.w == -1.0f);
      float iy = fmaxf(fminf(A.z, gg.z) - fmaxf(A.x, gg.x), 0.0f);
      float ix = fmaxf(fminf(A.w, gg.w) - fmaxf(A.y, gg.y), 0.0f);
      float inter = iy * ix;
      float uni = (aar + sab[j]) - inter;
      float iou = inter / fmaxf(uni, 1e-8f);
      if (ma || mj) iou = -1.0f;
      if (iou > bb) { bb = iou; cc = j; }   // ascending strict > = first-max
    }
    code = (bb >= 0.5f) ? 3 : ((bb >= 0.0f) ? 1 : 0);
  }

  float2 nz = reinterpret_cast<const float2*>(noise)[(size_t)b * NALL + i];
  float v = (code == 3) ? nz.x : nz.y;
  int bin = (int)(v * 1024.0f);
  bin = bin < 0 ? 0 : (bin > 1023 ? 1023 : bin);
  mword[(size_t)b * NALL + i] = cc | (code << 7) | (bin << 9);
}

// ---------------- shfl-based block inclusive scan (TS=1024, 16 waves) -------
__device__ __forceinline__ int block_incl_scan(int v, int tid, int* wsum) {
  __syncthreads();  // protect wsum reuse across consecutive calls
  int s = v;
  #pragma unroll
  for (int off = 1; off < 64; off <<= 1) {
    int u = __shfl_up(s, off);
    if ((tid & 63) >= off) s += u;
  }
  const int wid = tid >> 6;
  if ((tid & 63) == 63) wsum[wid] = s;
  __syncthreads();
  if (wid == 0) {
    const int lane = tid & 63;
    int w = (lane < (TS >> 6)) ? wsum[lane] : 0;
    #pragma unroll
    for (int off = 1; off < (TS >> 6); off <<= 1) {
      int u = __shfl_up(w, off);
      if (lane >= off) w += u;
    }
    if (lane < (TS >> 6)) wsum[lane] = w;
  }
  __syncthreads();
  return s + (wid ? wsum[wid - 1] : 0);
}

// ---------------- Kernel 2: balanced sampling + ordering + gather ------------
__global__ __launch_bounds__(TS) void k_select(
    const int* __restrict__ mword,
    const float* __restrict__ noise,  // B,NALL,2
    const float* __restrict__ rois,
    const float* __restrict__ gt,
    const float* __restrict__ gtcls,  // B,NGT,1
    float* __restrict__ out)
{
  #pragma clang fp contract(off)
  const int b = blockIdx.x;
  const int tid = threadIdx.x;

  __shared__ int hist[1024];            // packed pos|neg<<16
  __shared__ int wsum[TS >> 6];
  __shared__ int s_total;               // packed totals
  __shared__ float bval[2][BCAP];
  __shared__ int bidx_[2][BCAP];
  __shared__ int bcnt[2];
  __shared__ int s_bstar[2], s_need[2];
  __shared__ unsigned char ind[NALL];
  __shared__ unsigned short sorder[NSAMP];

  int ew[CH];     // packed word; bit7 set => candidate

  hist[tid] = 0;
  if (tid < 2) bcnt[tid] = 0;

  // ---- pass 1: one int load per element; histogram + ind init ----
  #pragma unroll
  for (int k = 0; k < CH; ++k) {
    const int i = tid + k * TS;
    int w = 0;
    if (i < NALL) {
      ind[i] = 0;
      w = mword[(size_t)b * NALL + i];
    }
    ew[k] = w;
  }
  __syncthreads();
  #pragma unroll
  for (int k = 0; k < CH; ++k) {
    const int w = ew[k];
    if (w & 0x80) atomicAdd(&hist[w >> 9], (w & 0x100) ? 1 : (1 << 16));
  }
  __syncthreads();

  // ---- packed suffix scan, one bin per thread ----
  const int c = hist[tid];
  const int incl = block_incl_scan(c, tid, wsum);
  if (tid == TS - 1) s_total = incl;
  __syncthreads();
  const int total = s_total;

  #pragma unroll
  for (int p = 0; p < 2; ++p) {
    const int want = p ? KNEG : KPOS;
    const int sh = p ? 16 : 0;
    const int tot = (total >> sh) & 0xFFFF;
    if (tot >= want) {                              // !selall
      const int inc = (incl >> sh) & 0xFFFF;
      const int cp = (c >> sh) & 0xFFFF;
      const int above = tot - inc;                  // sum of bins > tid
      if (above < want && above + cp >= want) {     // unique boundary thread
        s_bstar[p] = tid; s_need[p] = want - above;
      }
    }
  }
  __syncthreads();

  const bool selall0 = ((total & 0xFFFF) < KPOS);
  const bool selall1 = (((total >> 16) & 0xFFFF) < KNEG);

  // ---- mark: bins above boundary selected; boundary bins collected ----
  #pragma unroll
  for (int k = 0; k < CH; ++k) {
    const int w = ew[k];
    if (w & 0x80) {
      const int i = tid + k * TS;
      const int p = (w & 0x100) ? 0 : 1;
      const bool selall = p ? selall1 : selall0;
      const int bin = w >> 9;
      if (selall || bin > s_bstar[p]) {
        ind[i] = 1;
      } else if (bin == s_bstar[p]) {
        int pos = atomicAdd(&bcnt[p], 1);
        if (pos < BCAP) {
          bval[p][pos] = noise[((size_t)b * NALL + i) * 2 + p];  // rare reload
          bidx_[p][pos] = i;
        }
      }
    }
  }
  __syncthreads();

  // ---- boundary-bin exact top-k via parallel rank (value desc, idx asc) ----
  #pragma unroll
  for (int p = 0; p < 2; ++p) {
    const bool selall = p ? selall1 : selall0;
    if (selall) continue;
    int cnt = bcnt[p]; if (cnt > BCAP) cnt = BCAP;
    const int need = s_need[p];
    for (int x = tid; x < cnt; x += TS) {
      const float v = bval[p][x];
      const int id = bidx_[p][x];
      int rank = 0;
      for (int y = 0; y < cnt; ++y) {
        const float vy = bval[p][y];
        const int iy2 = bidx_[p][y];
        rank += (vy > v) || (vy == v && iy2 < id);
      }
      if (rank < need) ind[id] = 1;
    }
  }
  __syncthreads();

  // ---- ordering: ones ascending then zeros ascending (top_k of 0/1) ----
  const int start = tid * CH;
  const int end = (start + CH < NALL) ? (start + CH) : NALL;
  int cnt1 = 0;
  for (int i = start; i < end; ++i) cnt1 += ind[i];
  const int incl1 = block_incl_scan(cnt1, tid, wsum);
  if (tid == TS - 1) s_total = incl1;
  __syncthreads();
  const int K1 = s_total;
  int ones_before = incl1 - cnt1;
  const int nzero = NSAMP - K1;
  for (int i = start; i < end; ++i) {
    if (ind[i]) {
      sorder[ones_before] = (unsigned short)i;
      ones_before++;
    } else {
      const int zrank = i - ones_before;
      if (zrank < nzero) sorder[K1 + zrank] = (unsigned short)i;
    }
  }
  __syncthreads();

  // ---- fused gather + encode + write (one sample per thread) ----
  if (tid < NSAMP) {
    const int s = tid;
    const int idx = sorder[s];
    const size_t t = (size_t)b * NSAMP + s;

    float4 A = (idx < NROIS)
      ? reinterpret_cast<const float4*>(rois)[(size_t)b * NROIS + idx]
      : reinterpret_cast<const float4*>(gt)[(size_t)b * NGT + (idx - NROIS)];

    const int w = mword[(size_t)b * NALL + idx];
    const int col = w & 0x7F;
    const bool pos = (((w >> 7) & 3) == 3);

    float e0 = 0.f, e1 = 0.f, e2 = 0.f, e3 = 0.f, cls = 0.f;
    if (pos) {
      float4 G = reinterpret_cast<const float4*>(gt)[(size_t)b * NGT + col];
      float ah = A.z - A.x, aw = A.w - A.y;
      float acy = A.x + 0.5f * ah, acx = A.y + 0.5f * aw;
      float bh = G.z - G.x, bw = G.w - G.y;
      float bcy = G.x + 0.5f * bh, bcx = G.y + 0.5f * bw;
      e0 = ((bcy - acy) / ah) / 0.1f;
      e1 = ((bcx - acx) / aw) / 0.1f;
      e2 = logf(bh / ah) / 0.2f;
      e3 = logf(bw / aw) / 0.2f;
      cls = gtcls[(size_t)b * NGT + col];
    }

    float* o_rois = out;                           // NB*NSAMP*4
    float* o_enc  = out + (size_t)NB * NSAMP * 4;  // NB*NSAMP*4
    float* o_bw   = out + (size_t)NB * NSAMP * 8;
    float* o_cls  = o_bw + (size_t)NB * NSAMP;
    float* o_cw   = o_cls + (size_t)NB * NSAMP;

    reinterpret_cast<float4*>(o_rois)[t] = A;
    float4 E; E.x = e0; E.y = e1; E.z = e2; E.w = e3;
    reinterpret_cast<float4*>(o_enc)[t] = E;
    o_bw[t]  = pos ? 1.0f : 0.0f;
    o_cls[t] = cls;
    o_cw[t]  = (s < K1) ? 1.0f : 0.0f;
  }
}

extern "C" void kernel_launch(void* const* d_in, const int* in_sizes, int n_in,
                              void* d_out, int out_size, void* d_ws, size_t ws_size,
                              hipStream_t stream) {
  const float* rois  = (const float*)d_in[0];
  const float* gt    = (const float*)d_in[1];
  const float* gtcls = (const float*)d_in[2];
  const float* noise = (const float*)d_in[3];
  float* out = (float*)d_out;

  int* mword = (int*)d_ws;  // NB*NALL ints

  dim3 g1(NALL / 128, NB);  // (65, 32) = 2080 blocks, 2 waves each
  k_match<<<g1, 128, 0, stream>>>(rois, gt, noise, mword);
  k_select<<<NB, TS, 0, stream>>>(mword, noise, rois, gt, gtcls, out);
}